// Round 1
// baseline (341.518 us; speedup 1.0000x reference)
//
#include <hip/hip_runtime.h>
#include <hip/hip_bf16.h>
#include <math.h>

// entmax-1.5 rows of 4096 x 32000 f32.
// One block per row; row kept in registers (8 float4/thread @ 1024 threads).
// tau solved over the candidate set {x > xmax-2} (provably a superset of the
// support since tau in [-1,0] on the z=(x-xmax)/2 scale).

#define ROWLEN 32000
#define ROWV4  (ROWLEN / 4)   // 8000
#define BLOCK  1024
#define NV4    8              // ceil(8000/1024)
#define NW     (BLOCK / 64)   // 16 waves
#define CAND_MAX 4096

__global__ __launch_bounds__(BLOCK)
void entmax15_kernel(const float* __restrict__ x, float* __restrict__ out) {
  const int row  = blockIdx.x;
  const float4* __restrict__ xr   = (const float4*)(x   + (size_t)row * ROWLEN);
  float4*       __restrict__ outr = (float4*)      (out + (size_t)row * ROWLEN);
  const int t    = threadIdx.x;
  const int lane = t & 63;
  const int wid  = t >> 6;

  __shared__ float s_max[NW];
  __shared__ int   s_wtot[NW];
  __shared__ float s_red[3][NW];
  __shared__ float s_cand[CAND_MAX];

  // ---- load row into registers, local max ----
  float4 v[NV4];
  float lmax = -1e30f;
#pragma unroll
  for (int i = 0; i < NV4; ++i) {
    int idx = i * BLOCK + t;
    if (idx < ROWV4) {
      v[i] = xr[idx];
      lmax = fmaxf(lmax, fmaxf(fmaxf(v[i].x, v[i].y), fmaxf(v[i].z, v[i].w)));
    }
  }
#pragma unroll
  for (int m = 32; m >= 1; m >>= 1) lmax = fmaxf(lmax, __shfl_xor(lmax, m));
  if (lane == 0) s_max[wid] = lmax;
  __syncthreads();
  float xmax = s_max[0];
#pragma unroll
  for (int w = 1; w < NW; ++w) xmax = fmaxf(xmax, s_max[w]);
  const float thr = xmax - 2.0f;   // z > -1  <=>  x > xmax - 2

  // ---- count candidates per thread ----
  int c = 0;
#pragma unroll
  for (int i = 0; i < NV4; ++i) {
    int idx = i * BLOCK + t;
    if (idx < ROWV4) {
      c += (v[i].x > thr) + (v[i].y > thr) + (v[i].z > thr) + (v[i].w > thr);
    }
  }
  // wave inclusive scan of c
  int incl = c;
#pragma unroll
  for (int m = 1; m < 64; m <<= 1) {
    int nb = __shfl_up(incl, m);
    if (lane >= m) incl += nb;
  }
  if (lane == 63) s_wtot[wid] = incl;
  __syncthreads();
  int wbase = 0, total = 0;
#pragma unroll
  for (int w = 0; w < NW; ++w) {
    int wt = s_wtot[w];
    if (w < wid) wbase += wt;
    total += wt;
  }
  const bool compact = (total <= CAND_MAX);

  // ---- gather candidates (z-scale) into LDS ----
  if (compact) {
    int off = wbase + incl - c;
#pragma unroll
    for (int i = 0; i < NV4; ++i) {
      int idx = i * BLOCK + t;
      if (idx < ROWV4) {
        float a;
        a = v[i].x; if (a > thr) s_cand[off++] = (a - xmax) * 0.5f;
        a = v[i].y; if (a > thr) s_cand[off++] = (a - xmax) * 0.5f;
        a = v[i].z; if (a > thr) s_cand[off++] = (a - xmax) * 0.5f;
        a = v[i].w; if (a > thr) s_cand[off++] = (a - xmax) * 0.5f;
      }
    }
  }
  __syncthreads();

  // my candidate subset in registers (<= 4 each)
  float myz[4];
  int nmy = 0;
  if (compact) {
    for (int idx = t; idx < total; idx += BLOCK) myz[nmy++] = s_cand[idx];
  }

  // ---- Newton on f(tau) = sum max(z-tau,0)^2 - 1, from tau=-1 (left side) ----
  float tau = -1.0f;
  for (int it = 0; it < 8; ++it) {
    float s = 0.f, q = 0.f;
    if (compact) {
      for (int j = 0; j < nmy; ++j) {
        float d = myz[j] - tau;
        if (d > 0.f) { s += d; q += d * d; }
      }
    } else {
#pragma unroll
      for (int i = 0; i < NV4; ++i) {
        int idx = i * BLOCK + t;
        if (idx < ROWV4) {
          float d;
          d = (v[i].x - xmax) * 0.5f - tau; if (d > 0.f) { s += d; q += d * d; }
          d = (v[i].y - xmax) * 0.5f - tau; if (d > 0.f) { s += d; q += d * d; }
          d = (v[i].z - xmax) * 0.5f - tau; if (d > 0.f) { s += d; q += d * d; }
          d = (v[i].w - xmax) * 0.5f - tau; if (d > 0.f) { s += d; q += d * d; }
        }
      }
    }
#pragma unroll
    for (int m = 32; m >= 1; m >>= 1) {
      s += __shfl_xor(s, m);
      q += __shfl_xor(q, m);
    }
    if (lane == 0) { s_red[0][wid] = s; s_red[1][wid] = q; }
    __syncthreads();
    s = 0.f; q = 0.f;
#pragma unroll
    for (int w = 0; w < NW; ++w) { s += s_red[0][w]; q += s_red[1][w]; }
    __syncthreads();
    if (s > 0.f) tau += (q - 1.0f) / (2.0f * s);
  }

  // ---- closed-form polish with the resolved support ----
  float k = 0.f, s1 = 0.f, s2 = 0.f;
  if (compact) {
    for (int j = 0; j < nmy; ++j) {
      float z = myz[j];
      if (z > tau) { k += 1.f; s1 += z; s2 += z * z; }
    }
  } else {
#pragma unroll
    for (int i = 0; i < NV4; ++i) {
      int idx = i * BLOCK + t;
      if (idx < ROWV4) {
        float z;
        z = (v[i].x - xmax) * 0.5f; if (z > tau) { k += 1.f; s1 += z; s2 += z * z; }
        z = (v[i].y - xmax) * 0.5f; if (z > tau) { k += 1.f; s1 += z; s2 += z * z; }
        z = (v[i].z - xmax) * 0.5f; if (z > tau) { k += 1.f; s1 += z; s2 += z * z; }
        z = (v[i].w - xmax) * 0.5f; if (z > tau) { k += 1.f; s1 += z; s2 += z * z; }
      }
    }
  }
#pragma unroll
  for (int m = 32; m >= 1; m >>= 1) {
    k  += __shfl_xor(k, m);
    s1 += __shfl_xor(s1, m);
    s2 += __shfl_xor(s2, m);
  }
  if (lane == 0) { s_red[0][wid] = k; s_red[1][wid] = s1; s_red[2][wid] = s2; }
  __syncthreads();
  k = 0.f; s1 = 0.f; s2 = 0.f;
#pragma unroll
  for (int w = 0; w < NW; ++w) { k += s_red[0][w]; s1 += s_red[1][w]; s2 += s_red[2][w]; }

  float disc = s1 * s1 - k * (s2 - 1.0f);
  float tau_star = (s1 - sqrtf(fmaxf(disc, 0.f))) / k;

  // ---- output p = max(z - tau, 0)^2 ----
#pragma unroll
  for (int i = 0; i < NV4; ++i) {
    int idx = i * BLOCK + t;
    if (idx < ROWV4) {
      float4 o;
      float d;
      d = (v[i].x - xmax) * 0.5f - tau_star; o.x = d > 0.f ? d * d : 0.f;
      d = (v[i].y - xmax) * 0.5f - tau_star; o.y = d > 0.f ? d * d : 0.f;
      d = (v[i].z - xmax) * 0.5f - tau_star; o.z = d > 0.f ? d * d : 0.f;
      d = (v[i].w - xmax) * 0.5f - tau_star; o.w = d > 0.f ? d * d : 0.f;
      outr[idx] = o;
    }
  }
}

extern "C" void kernel_launch(void* const* d_in, const int* in_sizes, int n_in,
                              void* d_out, int out_size, void* d_ws, size_t ws_size,
                              hipStream_t stream) {
  const float* x = (const float*)d_in[0];
  float* out = (float*)d_out;
  int rows = in_sizes[0] / ROWLEN;
  hipLaunchKernelGGL(entmax15_kernel, dim3(rows), dim3(BLOCK), 0, stream, x, out);
}

// Round 2
// 295.274 us; speedup vs baseline: 1.1566x; 1.1566x over previous
//
#include <hip/hip_runtime.h>
#include <hip/hip_bf16.h>
#include <math.h>

// entmax-1.5 rows of 4096 x 32000 f32.
// One block per row; row kept in registers (8 float4/thread @ 1024 threads).
// tau solved IN WAVE 0 ONLY over the candidate set {x > xmax-2} gathered to
// LDS (tau* in [-1,0] on the z=(x-xmax)/2 scale => candidates is a superset
// of the support). Only 3 block barriers total.

#define ROWLEN 32000
#define ROWV4  (ROWLEN / 4)   // 8000
#define BLOCK  1024
#define NV4    8              // ceil(8000/1024)
#define NW     (BLOCK / 64)   // 16 waves
#define CAND_MAX 4096

__global__ __launch_bounds__(BLOCK)
void entmax15_kernel(const float* __restrict__ x, float* __restrict__ out) {
  const int row  = blockIdx.x;
  const float4* __restrict__ xr   = (const float4*)(x   + (size_t)row * ROWLEN);
  float4*       __restrict__ outr = (float4*)      (out + (size_t)row * ROWLEN);
  const int t    = threadIdx.x;
  const int lane = t & 63;
  const int wid  = t >> 6;

  __shared__ float s_max[NW];
  __shared__ int   s_total;
  __shared__ float s_tau;
  __shared__ float s_red[3][NW];
  __shared__ float s_cand[CAND_MAX];

  if (t == 0) s_total = 0;

  // ---- load row into registers, local max ----
  float4 v[NV4];
  float lmax = -1e30f;
#pragma unroll
  for (int i = 0; i < NV4; ++i) {
    int idx = i * BLOCK + t;
    if (idx < ROWV4) {
      v[i] = xr[idx];
      lmax = fmaxf(lmax, fmaxf(fmaxf(v[i].x, v[i].y), fmaxf(v[i].z, v[i].w)));
    }
  }
#pragma unroll
  for (int m = 32; m >= 1; m >>= 1) lmax = fmaxf(lmax, __shfl_xor(lmax, m));
  if (lane == 0) s_max[wid] = lmax;
  __syncthreads();                       // barrier 1 (also covers s_total=0)
  float xmax = s_max[0];
#pragma unroll
  for (int w = 1; w < NW; ++w) xmax = fmaxf(xmax, s_max[w]);
  const float thr = xmax - 2.0f;   // z > -1  <=>  x > xmax - 2

  // ---- count candidates per thread ----
  int c = 0;
#pragma unroll
  for (int i = 0; i < NV4; ++i) {
    int idx = i * BLOCK + t;
    if (idx < ROWV4) {
      c += (v[i].x > thr) + (v[i].y > thr) + (v[i].z > thr) + (v[i].w > thr);
    }
  }
  // wave inclusive scan of c; wave base via one LDS atomic (order irrelevant)
  int incl = c;
#pragma unroll
  for (int m = 1; m < 64; m <<= 1) {
    int nb = __shfl_up(incl, m);
    if (lane >= m) incl += nb;
  }
  int wbase = 0;
  if (lane == 63) wbase = atomicAdd(&s_total, incl);
  wbase = __shfl(wbase, 63);

  // ---- gather candidates (z-scale) into LDS (guarded) ----
  {
    int off = wbase + incl - c;
#pragma unroll
    for (int i = 0; i < NV4; ++i) {
      int idx = i * BLOCK + t;
      if (idx < ROWV4) {
        float a;
        a = v[i].x; if (a > thr) { if (off < CAND_MAX) s_cand[off] = (a - xmax) * 0.5f; ++off; }
        a = v[i].y; if (a > thr) { if (off < CAND_MAX) s_cand[off] = (a - xmax) * 0.5f; ++off; }
        a = v[i].z; if (a > thr) { if (off < CAND_MAX) s_cand[off] = (a - xmax) * 0.5f; ++off; }
        a = v[i].w; if (a > thr) { if (off < CAND_MAX) s_cand[off] = (a - xmax) * 0.5f; ++off; }
      }
    }
  }
  __syncthreads();                       // barrier 2: candidates + total final
  const int total = s_total;

  if (total <= CAND_MAX) {
    // ---- tau solve entirely in wave 0: zero block barriers inside ----
    if (wid == 0) {
      float tau = -1.0f;
      // Newton on f(tau) = sum max(z-tau,0)^2 - 1 (convex, monotone from left)
      for (int it = 0; it < 8; ++it) {
        float s = 0.f, q = 0.f;
        for (int j = lane; j < total; j += 64) {
          float d = s_cand[j] - tau;
          if (d > 0.f) { s += d; q += d * d; }
        }
#pragma unroll
        for (int m = 32; m >= 1; m >>= 1) {
          s += __shfl_xor(s, m);
          q += __shfl_xor(q, m);
        }
        if (s > 0.f) tau += (q - 1.0f) / (2.0f * s);
      }
      // closed-form support fix-point (matches reference formula exactly)
      for (int it = 0; it < 2; ++it) {
        float k = 0.f, s1 = 0.f, s2 = 0.f;
        for (int j = lane; j < total; j += 64) {
          float z = s_cand[j];
          if (z > tau) { k += 1.f; s1 += z; s2 += z * z; }
        }
#pragma unroll
        for (int m = 32; m >= 1; m >>= 1) {
          k  += __shfl_xor(k, m);
          s1 += __shfl_xor(s1, m);
          s2 += __shfl_xor(s2, m);
        }
        float disc = s1 * s1 - k * (s2 - 1.0f);
        tau = (s1 - sqrtf(fmaxf(disc, 0.f))) / k;
      }
      if (lane == 0) s_tau = tau;
    }
  } else {
    // ---- fallback (shouldn't trigger for N(0,1) rows): block-wide Newton ----
    float tau = -1.0f;
    for (int it = 0; it < 8; ++it) {
      float s = 0.f, q = 0.f;
#pragma unroll
      for (int i = 0; i < NV4; ++i) {
        int idx = i * BLOCK + t;
        if (idx < ROWV4) {
          float d;
          d = (v[i].x - xmax) * 0.5f - tau; if (d > 0.f) { s += d; q += d * d; }
          d = (v[i].y - xmax) * 0.5f - tau; if (d > 0.f) { s += d; q += d * d; }
          d = (v[i].z - xmax) * 0.5f - tau; if (d > 0.f) { s += d; q += d * d; }
          d = (v[i].w - xmax) * 0.5f - tau; if (d > 0.f) { s += d; q += d * d; }
        }
      }
#pragma unroll
      for (int m = 32; m >= 1; m >>= 1) {
        s += __shfl_xor(s, m);
        q += __shfl_xor(q, m);
      }
      if (lane == 0) { s_red[0][wid] = s; s_red[1][wid] = q; }
      __syncthreads();
      s = 0.f; q = 0.f;
#pragma unroll
      for (int w = 0; w < NW; ++w) { s += s_red[0][w]; q += s_red[1][w]; }
      __syncthreads();
      if (s > 0.f) tau += (q - 1.0f) / (2.0f * s);
    }
    float k = 0.f, s1 = 0.f, s2 = 0.f;
#pragma unroll
    for (int i = 0; i < NV4; ++i) {
      int idx = i * BLOCK + t;
      if (idx < ROWV4) {
        float z;
        z = (v[i].x - xmax) * 0.5f; if (z > tau) { k += 1.f; s1 += z; s2 += z * z; }
        z = (v[i].y - xmax) * 0.5f; if (z > tau) { k += 1.f; s1 += z; s2 += z * z; }
        z = (v[i].z - xmax) * 0.5f; if (z > tau) { k += 1.f; s1 += z; s2 += z * z; }
        z = (v[i].w - xmax) * 0.5f; if (z > tau) { k += 1.f; s1 += z; s2 += z * z; }
      }
    }
#pragma unroll
    for (int m = 32; m >= 1; m >>= 1) {
      k  += __shfl_xor(k, m);
      s1 += __shfl_xor(s1, m);
      s2 += __shfl_xor(s2, m);
    }
    if (lane == 0) { s_red[0][wid] = k; s_red[1][wid] = s1; s_red[2][wid] = s2; }
    __syncthreads();
    k = 0.f; s1 = 0.f; s2 = 0.f;
#pragma unroll
    for (int w = 0; w < NW; ++w) { k += s_red[0][w]; s1 += s_red[1][w]; s2 += s_red[2][w]; }
    float disc = s1 * s1 - k * (s2 - 1.0f);
    if (t == 0) s_tau = (s1 - sqrtf(fmaxf(disc, 0.f))) / k;
  }
  __syncthreads();                       // barrier 3: tau ready
  const float cc = fmaf(xmax, 0.5f, s_tau);   // d = x*0.5 - cc

  // ---- output p = max(x*0.5 - cc, 0)^2 ----
#pragma unroll
  for (int i = 0; i < NV4; ++i) {
    int idx = i * BLOCK + t;
    if (idx < ROWV4) {
      float4 o;
      float d;
      d = fmaf(v[i].x, 0.5f, -cc); o.x = d > 0.f ? d * d : 0.f;
      d = fmaf(v[i].y, 0.5f, -cc); o.y = d > 0.f ? d * d : 0.f;
      d = fmaf(v[i].z, 0.5f, -cc); o.z = d > 0.f ? d * d : 0.f;
      d = fmaf(v[i].w, 0.5f, -cc); o.w = d > 0.f ? d * d : 0.f;
      outr[idx] = o;
    }
  }
}

extern "C" void kernel_launch(void* const* d_in, const int* in_sizes, int n_in,
                              void* d_out, int out_size, void* d_ws, size_t ws_size,
                              hipStream_t stream) {
  const float* x = (const float*)d_in[0];
  float* out = (float*)d_out;
  int rows = in_sizes[0] / ROWLEN;
  hipLaunchKernelGGL(entmax15_kernel, dim3(rows), dim3(BLOCK), 0, stream, x, out);
}